// Round 10
// baseline (321.481 us; speedup 1.0000x reference)
//
#include <hip/hip_runtime.h>

#define N 4096
#define TSTEPS 3
#define FEAT 36
#define NVIS 6
#define HID 256
#define DIN 18   // TSTEPS*NVIS
#define DOUT 2
#define HT 2048  // (fallback kernel) half-tile staged in LDS

typedef __attribute__((ext_vector_type(8))) short bf16x8;   // 8 bf16 = 4 VGPR
typedef __attribute__((ext_vector_type(4))) float f32x4;

__device__ __forceinline__ short f2bf(float f) {
    unsigned u = __builtin_bit_cast(unsigned, f);
    unsigned r = (u + 0x7FFFu + ((u >> 16) & 1u)) >> 16;   // RNE
    return (short)r;
}

// ---------------- Prep: vis -> xallT[c][j] (transposed)  +  W1,W2 frags -----
__global__ void k_prep(const float* __restrict__ vis, const float* __restrict__ Wv,
                       const float* __restrict__ bv, float* __restrict__ xallT,
                       const float* __restrict__ W1, const float* __restrict__ W2,
                       short* __restrict__ Wp) {
    if (blockIdx.x < 288) {
        int o = blockIdx.x * 256 + threadIdx.x;   // 0..73727
        int c = o >> 12;                          // 0..17
        int j = o & 4095;
        int t  = c / NVIS;
        int cc = c - t * NVIS;
        const float* vrow = vis + (size_t)j * (TSTEPS * FEAT) + t * FEAT;
        float acc = bv[cc];
#pragma unroll
        for (int f = 0; f < FEAT; ++f) acc += vrow[f] * Wv[f * NVIS + cc];
        xallT[(size_t)c * N + j] = acc;           // coalesced along j
    } else {
        int t = (blockIdx.x - 288) * 256 + threadIdx.x;   // 0..131071
        int L  = t >> 16;
        int e  = t & 65535;
        int jj = e & 7;
        int l  = (e >> 3) & 63;
        int j  = (e >> 9) & 15;
        int s  = e >> 13;
        int k  = s * 32 + ((l >> 4) << 3) + jj;
        int n  = (j << 4) + (l & 15);
        const float* W = L ? W2 : W1;
        Wp[t] = f2bf(W[k * HID + n]);
    }
}

// One chunk of a-data: 2 rows x 12 consecutive floats (4 j's) per lane.
struct AChunk { float4 u0, u1, u2, v0, v1, v2; };

__device__ __forceinline__ AChunk aload(const float* __restrict__ a0,
                                        const float* __restrict__ a1,
                                        int fbase) {
    AChunk d;
    const float4* p0 = (const float4*)(a0 + fbase);
    const float4* p1 = (const float4*)(a1 + fbase);
    d.u0 = p0[0]; d.u1 = p0[1]; d.u2 = p0[2];
    d.v0 = p1[0]; d.v1 = p1[1]; d.v2 = p1[2];
    return d;
}

// ---------------- Main stream: LDS-free, 2 j-slabs, partials to ws ----------
// 1024 blocks x 256 thr, 16 waves/CU (all co-resident). Wave owns 2 rows x
// one 2048-j slab; 8 chunks of 256 j; a 2-deep prefetched; x from L2 coalesced.
__global__ __launch_bounds__(256, 4)
void k_msg2(const float* __restrict__ a, const float* __restrict__ xallT,
            float* __restrict__ pw) {
    const int tid  = threadIdx.x;
    const int lane = tid & 63;
    const int wave = tid >> 6;
    const int rg   = blockIdx.x >> 1;
    const int slab = blockIdx.x & 1;
    const int row_base = rg * 8 + wave * 2;

    const float* a0 = a + (size_t)row_base       * (N * 3);
    const float* a1 = a + (size_t)(row_base + 1) * (N * 3);
    const float4* xT4 = (const float4*)xallT;     // [18][1024] float4

    float acc[2][3][6];
    float s[2][2];
#pragma unroll
    for (int r = 0; r < 2; ++r) {
#pragma unroll
        for (int t = 0; t < 3; ++t)
#pragma unroll
            for (int c = 0; c < 6; ++c) acc[r][t][c] = 0.f;
        s[r][0] = 0.f; s[r][1] = 0.f;
    }

    const int j0base = slab * 2048 + lane * 4;    // + ch*256
    AChunk cur = aload(a0, a1, j0base * 3);
#pragma unroll
    for (int ch = 0; ch < 8; ++ch) {
        AChunk nxt;
        if (ch + 1 < 8) nxt = aload(a0, a1, (j0base + (ch + 1) * 256) * 3);

        const float av0[4][3] = {{cur.u0.x,cur.u0.y,cur.u0.z},{cur.u0.w,cur.u1.x,cur.u1.y},
                                 {cur.u1.z,cur.u1.w,cur.u2.x},{cur.u2.y,cur.u2.z,cur.u2.w}};
        const float av1[4][3] = {{cur.v0.x,cur.v0.y,cur.v0.z},{cur.v0.w,cur.v1.x,cur.v1.y},
                                 {cur.v1.z,cur.v1.w,cur.v2.x},{cur.v2.y,cur.v2.z,cur.v2.w}};
        const int jv = slab * 512 + ch * 64 + lane;   // float4 index within row
#pragma unroll
        for (int t = 0; t < 3; ++t)
#pragma unroll
            for (int c = 0; c < 6; ++c) {
                float4 xv = xT4[(t * 6 + c) * 1024 + jv];
                acc[0][t][c] += av0[0][t] * xv.x + av0[1][t] * xv.y
                              + av0[2][t] * xv.z + av0[3][t] * xv.w;
                acc[1][t][c] += av1[0][t] * xv.x + av1[1][t] * xv.y
                              + av1[2][t] * xv.z + av1[3][t] * xv.w;
            }
#pragma unroll
        for (int q = 0; q < 4; ++q) {
            s[0][0] += av0[q][1]; s[0][1] += av0[q][2];
            s[1][0] += av1[q][1]; s[1][1] += av1[q][2];
        }
        cur = nxt;
    }

    // butterfly reduce across 64 lanes
#pragma unroll
    for (int m = 1; m < 64; m <<= 1) {
#pragma unroll
        for (int r = 0; r < 2; ++r) {
#pragma unroll
            for (int t = 0; t < 3; ++t)
#pragma unroll
                for (int c = 0; c < 6; ++c)
                    acc[r][t][c] += __shfl_xor(acc[r][t][c], m, 64);
            s[r][0] += __shfl_xor(s[r][0], m, 64);
            s[r][1] += __shfl_xor(s[r][1], m, 64);
        }
    }

    if (lane == 0) {
#pragma unroll
        for (int r = 0; r < 2; ++r) {
            float* o = pw + ((size_t)(slab * N) + row_base + r) * 20;
            *(float4*)(o)      = (float4){acc[r][0][0], acc[r][0][1], acc[r][0][2], acc[r][0][3]};
            *(float4*)(o + 4)  = (float4){acc[r][0][4], acc[r][0][5], acc[r][1][0], acc[r][1][1]};
            *(float4*)(o + 8)  = (float4){acc[r][1][2], acc[r][1][3], acc[r][1][4], acc[r][1][5]};
            *(float4*)(o + 12) = (float4){acc[r][2][0], acc[r][2][1], acc[r][2][2], acc[r][2][3]};
            *(float4*)(o + 16) = (float4){acc[r][2][4], acc[r][2][5], s[r][0], s[r][1]};
        }
    }
}

// ---------------- Final: sum slab partials -> xagg + MLP tail ---------------
__global__ __launch_bounds__(256)
void k_fin(const float* __restrict__ pw,
           const short* __restrict__ Wp,
           const float* __restrict__ W0, const float* __restrict__ b0,
           const float* __restrict__ b1, const float* __restrict__ b2,
           const float* __restrict__ Wpf, const float* __restrict__ bp,
           float* __restrict__ xagg, float* __restrict__ u_out) {
    __shared__ struct {
        float xa[8][DIN];
        short hA[16 * 256];
        short hB[16 * 256];
        float h3[16 * 257];
    } sm;
    __shared__ float tmp[8][20];
    const int tid  = threadIdx.x;
    const int lane = tid & 63;
    const int wave = tid >> 6;
    const int row0 = blockIdx.x * 8;

    if (tid < 160) {
        int r = tid / 20, e = tid - r * 20;
        tmp[r][e] = pw[(size_t)(row0 + r) * 20 + e]
                  + pw[(size_t)(N + row0 + r) * 20 + e];
    }
    __syncthreads();
    if (tid < 144) {
        int r = tid / 18, e = tid - r * 18;
        float s1 = tmp[r][18], s2 = tmp[r][19];
        float v;
        if (e < 6)       v = tmp[r][12 + e];
        else if (e < 12) v = tmp[r][e] * s2;
        else             v = tmp[r][e - 12] * s1 * s2;
        sm.xa[r][e] = v;
        xagg[(size_t)(row0 + r) * DIN + e] = v;
    }
    __syncthreads();

    { // ---- layer 0 (K=18, f32 VALU): thread -> 1 row x 8 neurons ----
        const int row = tid >> 5;            // 0..7
        const int n0  = (tid & 31) * 8;
        float accv[8];
#pragma unroll
        for (int jn = 0; jn < 8; ++jn) accv[jn] = b0[n0 + jn];
        for (int k = 0; k < DIN; ++k) {
            float4 wa = *(const float4*)&W0[k * HID + n0];
            float4 wb = *(const float4*)&W0[k * HID + n0 + 4];
            const float w[8] = {wa.x,wa.y,wa.z,wa.w, wb.x,wb.y,wb.z,wb.w};
            float xr = sm.xa[row][k];
#pragma unroll
            for (int jn = 0; jn < 8; ++jn) accv[jn] += xr * w[jn];
        }
        bf16x8 v;
#pragma unroll
        for (int jn = 0; jn < 8; ++jn) v[jn] = f2bf(fmaxf(accv[jn], 0.f));
        *(bf16x8*)&sm.hA[(row * 256 + n0) ^ ((row & 7) << 3)] = v;
    }
    __syncthreads();

    // ---- layers 1 & 2: MFMA 16x16x32 bf16 (rows 8-15 garbage, confined) ----
    const int arow = lane & 15;
    const int kgrp = (lane >> 4) << 3;
    const int wv   = wave;
#pragma unroll 1
    for (int L = 0; L < 2; ++L) {
        const short* hsrc = L ? sm.hB : sm.hA;
        const float* bias = L ? b2 : b1;
        const short* WpL  = Wp + L * 65536;

        bf16x8 Af[8];
#pragma unroll
        for (int ks = 0; ks < 8; ++ks)
            Af[ks] = *(const bf16x8*)&hsrc[(arow * 256 + ks * 32 + kgrp) ^ ((arow & 7) << 3)];

        f32x4 c4[4];
#pragma unroll
        for (int jt = 0; jt < 4; ++jt) {
            float b = bias[wv * 64 + jt * 16 + (lane & 15)];
            c4[jt] = (f32x4){b, b, b, b};
        }
#pragma unroll
        for (int ks = 0; ks < 8; ++ks) {
#pragma unroll
            for (int jt = 0; jt < 4; ++jt) {
                int j = wv * 4 + jt;
                bf16x8 Bf = *(const bf16x8*)&WpL[(((ks * 16 + j) * 64) + lane) * 8];
                c4[jt] = __builtin_amdgcn_mfma_f32_16x16x32_bf16(Af[ks], Bf, c4[jt], 0, 0, 0);
            }
        }
#pragma unroll
        for (int jt = 0; jt < 4; ++jt) {
            int n = wv * 64 + jt * 16 + (lane & 15);
#pragma unroll
            for (int q = 0; q < 4; ++q) {
                int row = ((lane >> 4) << 2) + q;
                float v = fmaxf(c4[jt][q], 0.f);
                if (L == 0) sm.hB[(row * 256 + n) ^ ((row & 7) << 3)] = f2bf(v);
                else        sm.h3[row * 257 + n] = v;
            }
        }
        __syncthreads();
    }

    // ---- final layer 256 -> 2 for 8 rows: tid = r*16 + d*8 + ks ----
    if (tid < 128) {
        const int r  = tid >> 4;        // 0..7
        const int d  = (tid >> 3) & 1;
        const int ks = tid & 7;
        float accf = 0.f;
        const float* hr = &sm.h3[r * 257 + ks * 32];
#pragma unroll
        for (int i = 0; i < 32; ++i) accf += hr[i] * Wpf[(ks * 32 + i) * DOUT + d];
        accf += __shfl_xor(accf, 1, 64);
        accf += __shfl_xor(accf, 2, 64);
        accf += __shfl_xor(accf, 4, 64);
        if (ks == 0) u_out[(size_t)(row0 + r) * DOUT + d] = accf + bp[d];
    }
}

// ---------------- Fallback (R9 path, only if workspace too small) -----------
template<int FUSE>
__global__ __launch_bounds__(256, 1)
void k_msg_mlp(const float* __restrict__ a, const float* __restrict__ xallT,
               float* __restrict__ xagg,
               const short* __restrict__ Wp,
               const float* __restrict__ W0, const float* __restrict__ b0,
               const float* __restrict__ b1, const float* __restrict__ b2,
               const float* __restrict__ Wpf, const float* __restrict__ bp,
               float* __restrict__ u_out) {
    __shared__ union {
        float xT[DIN][HT];
        struct {
            float xa[8][DIN];
            short hA[16 * 256];
            short hB[16 * 256];
            float h3[16 * 257];
        } m;
    } sm;
    const int tid  = threadIdx.x;
    const int lane = tid & 63;
    const int wave = tid >> 6;
    const int row0 = blockIdx.x * 8;
    const int row_base = row0 + wave * 2;

    const float* a0 = a + (size_t)row_base       * (N * 3);
    const float* a1 = a + (size_t)(row_base + 1) * (N * 3);

    float acc[2][3][6];
    float s[2][2];
#pragma unroll
    for (int r = 0; r < 2; ++r) {
#pragma unroll
        for (int t = 0; t < 3; ++t)
#pragma unroll
            for (int c = 0; c < 6; ++c) acc[r][t][c] = 0.f;
        s[r][0] = 0.f; s[r][1] = 0.f;
    }

    AChunk p0 = aload(a0, a1, (lane * 4) * 3);
    AChunk p1 = aload(a0, a1, (256 + lane * 4) * 3);
    AChunk p2 = aload(a0, a1, (512 + lane * 4) * 3);

#pragma unroll
    for (int g = 0; g < 16; ++g) {
        if ((g & 7) == 0) {
            const int tile = g >> 3;
            __syncthreads();
#pragma unroll
            for (int k = 0; k < 36; ++k) {
                int idx = tid + k * 256;
                int c   = idx >> 9;
                int off = (idx & 511) << 2;
                *(float4*)&sm.xT[c][off] =
                    *(const float4*)&xallT[(size_t)c * N + tile * HT + off];
            }
            __syncthreads();
        }
        AChunk cur = p0; p0 = p1; p1 = p2;
        if (g + 3 < 16) p2 = aload(a0, a1, ((g + 3) * 256 + lane * 4) * 3);

        const float av0[4][3] = {{cur.u0.x,cur.u0.y,cur.u0.z},{cur.u0.w,cur.u1.x,cur.u1.y},
                                 {cur.u1.z,cur.u1.w,cur.u2.x},{cur.u2.y,cur.u2.z,cur.u2.w}};
        const float av1[4][3] = {{cur.v0.x,cur.v0.y,cur.v0.z},{cur.v0.w,cur.v1.x,cur.v1.y},
                                 {cur.v1.z,cur.v1.w,cur.v2.x},{cur.v2.y,cur.v2.z,cur.v2.w}};
        const int jb = (g & 7) * 256 + lane * 4;
#pragma unroll
        for (int t = 0; t < 3; ++t)
#pragma unroll
            for (int c = 0; c < 6; ++c) {
                float4 xv = *(const float4*)&sm.xT[t * 6 + c][jb];
                const float xq[4] = {xv.x, xv.y, xv.z, xv.w};
#pragma unroll
                for (int q = 0; q < 4; ++q) {
                    acc[0][t][c] += av0[q][t] * xq[q];
                    acc[1][t][c] += av1[q][t] * xq[q];
                }
            }
#pragma unroll
        for (int q = 0; q < 4; ++q) {
            s[0][0] += av0[q][1]; s[0][1] += av0[q][2];
            s[1][0] += av1[q][1]; s[1][1] += av1[q][2];
        }
    }

#pragma unroll
    for (int m = 1; m < 64; m <<= 1) {
#pragma unroll
        for (int r = 0; r < 2; ++r) {
#pragma unroll
            for (int t = 0; t < 3; ++t)
#pragma unroll
                for (int c = 0; c < 6; ++c)
                    acc[r][t][c] += __shfl_xor(acc[r][t][c], m, 64);
            s[r][0] += __shfl_xor(s[r][0], m, 64);
            s[r][1] += __shfl_xor(s[r][1], m, 64);
        }
    }

    __syncthreads();
    if (lane == 0) {
#pragma unroll
        for (int r = 0; r < 2; ++r) {
            const float s1 = s[r][0], s2 = s[r][1];
            float* xrow = sm.m.xa[wave * 2 + r];
#pragma unroll
            for (int c = 0; c < 6; ++c) {
                xrow[c]      = acc[r][2][c];
                xrow[6 + c]  = acc[r][1][c] * s2;
                xrow[12 + c] = acc[r][0][c] * s1 * s2;
            }
        }
    }
    __syncthreads();

    for (int idx = tid; idx < 8 * DIN; idx += 256) {
        int r = idx / DIN, e = idx - r * DIN;
        xagg[(size_t)(row0 + r) * DIN + e] = sm.m.xa[r][e];
    }

    if (!FUSE) return;

    {
        const int row = tid >> 5;
        const int n0  = (tid & 31) * 8;
        float accv[8];
#pragma unroll
        for (int jn = 0; jn < 8; ++jn) accv[jn] = b0[n0 + jn];
        for (int k = 0; k < DIN; ++k) {
            float4 wa = *(const float4*)&W0[k * HID + n0];
            float4 wb = *(const float4*)&W0[k * HID + n0 + 4];
            const float w[8] = {wa.x,wa.y,wa.z,wa.w, wb.x,wb.y,wb.z,wb.w};
            float xr = sm.m.xa[row][k];
#pragma unroll
            for (int jn = 0; jn < 8; ++jn) accv[jn] += xr * w[jn];
        }
        bf16x8 v;
#pragma unroll
        for (int jn = 0; jn < 8; ++jn) v[jn] = f2bf(fmaxf(accv[jn], 0.f));
        *(bf16x8*)&sm.m.hA[(row * 256 + n0) ^ ((row & 7) << 3)] = v;
    }
    __syncthreads();

    const int arow = lane & 15;
    const int kgrp = (lane >> 4) << 3;
    const int wv   = wave;
#pragma unroll 1
    for (int L = 0; L < 2; ++L) {
        const short* hsrc = L ? sm.m.hB : sm.m.hA;
        const float* bias = L ? b2 : b1;
        const short* WpL  = Wp + L * 65536;

        bf16x8 Af[8];
#pragma unroll
        for (int ks = 0; ks < 8; ++ks)
            Af[ks] = *(const bf16x8*)&hsrc[(arow * 256 + ks * 32 + kgrp) ^ ((arow & 7) << 3)];

        f32x4 c4[4];
#pragma unroll
        for (int jt = 0; jt < 4; ++jt) {
            float b = bias[wv * 64 + jt * 16 + (lane & 15)];
            c4[jt] = (f32x4){b, b, b, b};
        }
#pragma unroll
        for (int ks = 0; ks < 8; ++ks) {
#pragma unroll
            for (int jt = 0; jt < 4; ++jt) {
                int j = wv * 4 + jt;
                bf16x8 Bf = *(const bf16x8*)&WpL[(((ks * 16 + j) * 64) + lane) * 8];
                c4[jt] = __builtin_amdgcn_mfma_f32_16x16x32_bf16(Af[ks], Bf, c4[jt], 0, 0, 0);
            }
        }
#pragma unroll
        for (int jt = 0; jt < 4; ++jt) {
            int n = wv * 64 + jt * 16 + (lane & 15);
#pragma unroll
            for (int q = 0; q < 4; ++q) {
                int row = ((lane >> 4) << 2) + q;
                float v = fmaxf(c4[jt][q], 0.f);
                if (L == 0) sm.m.hB[(row * 256 + n) ^ ((row & 7) << 3)] = f2bf(v);
                else        sm.m.h3[row * 257 + n] = v;
            }
        }
        __syncthreads();
    }

    if (tid < 128) {
        const int r  = tid >> 4;
        const int d  = (tid >> 3) & 1;
        const int ks = tid & 7;
        float accf = 0.f;
        const float* hr = &sm.m.h3[r * 257 + ks * 32];
#pragma unroll
        for (int i = 0; i < 32; ++i) accf += hr[i] * Wpf[(ks * 32 + i) * DOUT + d];
        accf += __shfl_xor(accf, 1, 64);
        accf += __shfl_xor(accf, 2, 64);
        accf += __shfl_xor(accf, 4, 64);
        if (ks == 0) u_out[(size_t)(row0 + r) * DOUT + d] = accf + bp[d];
    }
}

extern "C" void kernel_launch(void* const* d_in, const int* in_sizes, int n_in,
                              void* d_out, int out_size, void* d_ws, size_t ws_size,
                              hipStream_t stream) {
    const float* vis  = (const float*)d_in[0];
    const float* anet = (const float*)d_in[1];
    const float* Wv   = (const float*)d_in[2];
    const float* bv   = (const float*)d_in[3];
    const float* W0   = (const float*)d_in[4];
    const float* b0   = (const float*)d_in[5];
    const float* W1   = (const float*)d_in[6];
    const float* b1   = (const float*)d_in[7];
    const float* W2   = (const float*)d_in[8];
    const float* b2   = (const float*)d_in[9];
    const float* Wpf  = (const float*)d_in[10];
    const float* bp   = (const float*)d_in[11];

    float* xagg  = (float*)d_out;                  // 4096*18
    float* u_out = (float*)d_out + (size_t)N*DIN;  // 4096*2
    float* xallT = (float*)d_ws;                   // 18*4096 transposed (288 KB)
    short* Wpk   = (short*)((char*)d_ws + (512 << 10));   // 256 KB bf16 frags
    float* pw    = (float*)((char*)d_ws + (768 << 10));   // 2*4096*20 f32 partials

    const size_t need_new = (768 << 10) + (size_t)2 * N * 20 * sizeof(float);
    const size_t need_old = (512 << 10) + 131072 * sizeof(short);

    if (ws_size >= need_new) {
        k_prep<<<800, 256, 0, stream>>>(vis, Wv, bv, xallT, W1, W2, Wpk);
        k_msg2<<<1024, 256, 0, stream>>>(anet, xallT, pw);
        k_fin<<<N / 8, 256, 0, stream>>>(pw, Wpk, W0, b0, b1, b2, Wpf, bp, xagg, u_out);
    } else if (ws_size >= need_old) {
        k_prep<<<800, 256, 0, stream>>>(vis, Wv, bv, xallT, W1, W2, Wpk);
        k_msg_mlp<1><<<N / 8, 256, 0, stream>>>(anet, xallT, xagg, Wpk,
                                                W0, b0, b1, b2, Wpf, bp, u_out);
    }
}

// Round 13
// 82.089 us; speedup vs baseline: 3.9163x; 3.9163x over previous
//
#include <hip/hip_runtime.h>

#define N 4096
#define TSTEPS 3
#define FEAT 36
#define NVIS 6
#define HID 256
#define DIN 18   // TSTEPS*NVIS
#define DOUT 2
#define SLABJ 512
#define NSLAB 8
#define SLABD 10752   // dwords per swizzled slab = 16 arenas * 672

typedef __attribute__((ext_vector_type(8))) short bf16x8;
typedef __attribute__((ext_vector_type(4))) float f32x4;

__device__ __forceinline__ short f2bf(float f) {
    unsigned u = __builtin_bit_cast(unsigned, f);
    unsigned r = (u + 0x7FFFu + ((u >> 16) & 1u)) >> 16;   // RNE
    return (short)r;
}

// R3-proven collision-free skewed layout for 512 rows x 18 floats.
__device__ __forceinline__ int srow(int r) {
    return (r >> 5) * 672 + (r & 31) * 20 + ((r >> 2) & 7) * 4;
}

// ---------------- Prep: x (linear + swizzled) and W1,W2 bf16 B-frags -------
__global__ void k_prep(const float* __restrict__ vis, const float* __restrict__ Wv,
                       const float* __restrict__ bv,
                       float* __restrict__ xallT, float* __restrict__ xsw,
                       const float* __restrict__ W1, const float* __restrict__ W2,
                       short* __restrict__ Wp) {
    if (blockIdx.x < 288) {
        int o = blockIdx.x * 256 + threadIdx.x;   // 0..73727
        if (o >= N * DIN) return;
        int j = o / DIN;
        int c = o - j * DIN;
        int t  = c / NVIS;
        int cc = c - t * NVIS;
        const float* vrow = vis + (size_t)j * (TSTEPS * FEAT) + t * FEAT;
        float acc = bv[cc];
#pragma unroll
        for (int f = 0; f < FEAT; ++f) acc += vrow[f] * Wv[f * NVIS + cc];
        xallT[(size_t)c * N + j] = acc;                                  // fallback layout
        xsw[(size_t)(j >> 9) * SLABD + srow(j & 511) + c] = acc;         // swizzled slabs
    } else {
        int t = (blockIdx.x - 288) * 256 + threadIdx.x;   // 0..131071
        int L  = t >> 16;
        int e  = t & 65535;
        int jj = e & 7;
        int l  = (e >> 3) & 63;
        int j  = (e >> 9) & 15;
        int s  = e >> 13;
        int k  = s * 32 + ((l >> 4) << 3) + jj;
        int n  = (j << 4) + (l & 15);
        const float* W = L ? W2 : W1;
        Wp[t] = f2bf(W[k * HID + n]);
    }
}

// ---------------- Main stream: one (rowgroup x slab) per block --------------
// 4096 blocks (slab-major) x 256 thr, 43KB LDS -> 3 blocks/CU, 12 waves/CU.
// Load EVERYTHING (12 a-float4/lane + x slab into LDS), one barrier, compute.
__global__ __launch_bounds__(256, 3)
void k_msga(const float* __restrict__ a, const float* __restrict__ xsw,
            float* __restrict__ pw) {
    __shared__ float xs[SLABD];                    // 43008 B
    const int tid  = threadIdx.x;
    const int lane = tid & 63;
    const int wave = tid >> 6;
    const int slab = blockIdx.x >> 9;              // slab-major for L2 reuse
    const int rg   = blockIdx.x & 511;
    const int row_base = rg * 8 + wave * 2;

    const float* a0 = a + (size_t)row_base * (N * 3) + slab * (SLABJ * 3);
    const float* a1 = a0 + N * 3;

    // issue all 12 a-loads (2 chunks x 2 rows x 3 float4), 6 KB in flight/wave
    float4 A[12];
    const int l4 = lane * 4;
#pragma unroll
    for (int ch = 0; ch < 2; ++ch) {
        const float4* p0 = (const float4*)(a0 + (size_t)(ch * 256 + l4) * 3);
        const float4* p1 = (const float4*)(a1 + (size_t)(ch * 256 + l4) * 3);
        A[ch * 6 + 0] = p0[0]; A[ch * 6 + 1] = p0[1]; A[ch * 6 + 2] = p0[2];
        A[ch * 6 + 3] = p1[0]; A[ch * 6 + 4] = p1[1]; A[ch * 6 + 5] = p1[2];
    }

    // stage the swizzled x slab: linear copy, coalesced loads, conflict-free writes
    {
        const float4* src = (const float4*)(xsw + (size_t)slab * SLABD);
        float4* dst = (float4*)xs;
#pragma unroll
        for (int it = 0; it < 11; ++it) {
            int idx = it * 256 + tid;
            if (idx < SLABD / 4) dst[idx] = src[idx];
        }
    }
    // keep-alive (input-only, SCALAR operands): force a-loads live pre-barrier
#pragma unroll
    for (int i = 0; i < 12; ++i)
        asm volatile("" :: "v"(A[i].x), "v"(A[i].y), "v"(A[i].z), "v"(A[i].w));
    __syncthreads();

    float acc[2][3][6];
    float s[2][2];
#pragma unroll
    for (int r = 0; r < 2; ++r) {
#pragma unroll
        for (int t = 0; t < 3; ++t)
#pragma unroll
            for (int c = 0; c < 6; ++c) acc[r][t][c] = 0.f;
        s[r][0] = 0.f; s[r][1] = 0.f;
    }

#pragma unroll
    for (int ch = 0; ch < 2; ++ch) {
        const float4 u0 = A[ch*6+0], u1 = A[ch*6+1], u2 = A[ch*6+2];
        const float4 v0 = A[ch*6+3], v1 = A[ch*6+4], v2 = A[ch*6+5];
        const float av0[4][3] = {{u0.x,u0.y,u0.z},{u0.w,u1.x,u1.y},
                                 {u1.z,u1.w,u2.x},{u2.y,u2.z,u2.w}};
        const float av1[4][3] = {{v0.x,v0.y,v0.z},{v0.w,v1.x,v1.y},
                                 {v1.z,v1.w,v2.x},{v2.y,v2.z,v2.w}};
#pragma unroll
        for (int q = 0; q < 4; ++q) {
            const float* xr = xs + srow(ch * 256 + l4 + q);
            float4 x0 = *(const float4*)(xr);
            float4 x1 = *(const float4*)(xr + 4);
            float4 x2 = *(const float4*)(xr + 8);
            float4 x3 = *(const float4*)(xr + 12);
            float2 x4 = *(const float2*)(xr + 16);
            const float xv[18] = {x0.x,x0.y,x0.z,x0.w, x1.x,x1.y,x1.z,x1.w,
                                  x2.x,x2.y,x2.z,x2.w, x3.x,x3.y,x3.z,x3.w,
                                  x4.x,x4.y};
#pragma unroll
            for (int t = 0; t < 3; ++t)
#pragma unroll
                for (int c = 0; c < 6; ++c) {
                    acc[0][t][c] += av0[q][t] * xv[t*6+c];
                    acc[1][t][c] += av1[q][t] * xv[t*6+c];
                }
            s[0][0] += av0[q][1]; s[0][1] += av0[q][2];
            s[1][0] += av1[q][1]; s[1][1] += av1[q][2];
        }
    }

    // butterfly reduce across 64 lanes
#pragma unroll
    for (int m = 1; m < 64; m <<= 1) {
#pragma unroll
        for (int r = 0; r < 2; ++r) {
#pragma unroll
            for (int t = 0; t < 3; ++t)
#pragma unroll
                for (int c = 0; c < 6; ++c)
                    acc[r][t][c] += __shfl_xor(acc[r][t][c], m, 64);
            s[r][0] += __shfl_xor(s[r][0], m, 64);
            s[r][1] += __shfl_xor(s[r][1], m, 64);
        }
    }

    if (lane == 0) {
#pragma unroll
        for (int r = 0; r < 2; ++r) {
            float* o = pw + ((size_t)slab * N + row_base + r) * 20;
            *(float4*)(o)      = (float4){acc[r][0][0], acc[r][0][1], acc[r][0][2], acc[r][0][3]};
            *(float4*)(o + 4)  = (float4){acc[r][0][4], acc[r][0][5], acc[r][1][0], acc[r][1][1]};
            *(float4*)(o + 8)  = (float4){acc[r][1][2], acc[r][1][3], acc[r][1][4], acc[r][1][5]};
            *(float4*)(o + 12) = (float4){acc[r][2][0], acc[r][2][1], acc[r][2][2], acc[r][2][3]};
            *(float4*)(o + 16) = (float4){acc[r][2][4], acc[r][2][5], s[r][0], s[r][1]};
        }
    }
}

// ---------------- Fallback stream (R10, proven-correct): 2 j-slabs ----------
struct AChunk { float4 u0, u1, u2, v0, v1, v2; };
__device__ __forceinline__ AChunk aload(const float* __restrict__ a0,
                                        const float* __restrict__ a1, int fbase) {
    AChunk d;
    const float4* p0 = (const float4*)(a0 + fbase);
    const float4* p1 = (const float4*)(a1 + fbase);
    d.u0 = p0[0]; d.u1 = p0[1]; d.u2 = p0[2];
    d.v0 = p1[0]; d.v1 = p1[1]; d.v2 = p1[2];
    return d;
}

__global__ __launch_bounds__(256, 4)
void k_msg2(const float* __restrict__ a, const float* __restrict__ xallT,
            float* __restrict__ pw) {
    const int tid  = threadIdx.x;
    const int lane = tid & 63;
    const int wave = tid >> 6;
    const int rg   = blockIdx.x >> 1;
    const int slab = blockIdx.x & 1;
    const int row_base = rg * 8 + wave * 2;

    const float* a0 = a + (size_t)row_base       * (N * 3);
    const float* a1 = a + (size_t)(row_base + 1) * (N * 3);
    const float4* xT4 = (const float4*)xallT;

    float acc[2][3][6];
    float s[2][2];
#pragma unroll
    for (int r = 0; r < 2; ++r) {
#pragma unroll
        for (int t = 0; t < 3; ++t)
#pragma unroll
            for (int c = 0; c < 6; ++c) acc[r][t][c] = 0.f;
        s[r][0] = 0.f; s[r][1] = 0.f;
    }

    const int j0base = slab * 2048 + lane * 4;
    AChunk cur = aload(a0, a1, j0base * 3);
#pragma unroll
    for (int ch = 0; ch < 8; ++ch) {
        AChunk nxt;
        if (ch + 1 < 8) nxt = aload(a0, a1, (j0base + (ch + 1) * 256) * 3);
        const float av0[4][3] = {{cur.u0.x,cur.u0.y,cur.u0.z},{cur.u0.w,cur.u1.x,cur.u1.y},
                                 {cur.u1.z,cur.u1.w,cur.u2.x},{cur.u2.y,cur.u2.z,cur.u2.w}};
        const float av1[4][3] = {{cur.v0.x,cur.v0.y,cur.v0.z},{cur.v0.w,cur.v1.x,cur.v1.y},
                                 {cur.v1.z,cur.v1.w,cur.v2.x},{cur.v2.y,cur.v2.z,cur.v2.w}};
        const int jv = slab * 512 + ch * 64 + lane;
#pragma unroll
        for (int t = 0; t < 3; ++t)
#pragma unroll
            for (int c = 0; c < 6; ++c) {
                float4 xv = xT4[(t * 6 + c) * 1024 + jv];
                acc[0][t][c] += av0[0][t] * xv.x + av0[1][t] * xv.y
                              + av0[2][t] * xv.z + av0[3][t] * xv.w;
                acc[1][t][c] += av1[0][t] * xv.x + av1[1][t] * xv.y
                              + av1[2][t] * xv.z + av1[3][t] * xv.w;
            }
#pragma unroll
        for (int q = 0; q < 4; ++q) {
            s[0][0] += av0[q][1]; s[0][1] += av0[q][2];
            s[1][0] += av1[q][1]; s[1][1] += av1[q][2];
        }
        cur = nxt;
    }

#pragma unroll
    for (int m = 1; m < 64; m <<= 1) {
#pragma unroll
        for (int r = 0; r < 2; ++r) {
#pragma unroll
            for (int t = 0; t < 3; ++t)
#pragma unroll
                for (int c = 0; c < 6; ++c)
                    acc[r][t][c] += __shfl_xor(acc[r][t][c], m, 64);
            s[r][0] += __shfl_xor(s[r][0], m, 64);
            s[r][1] += __shfl_xor(s[r][1], m, 64);
        }
    }

    if (lane == 0) {
#pragma unroll
        for (int r = 0; r < 2; ++r) {
            float* o = pw + ((size_t)(slab * N) + row_base + r) * 20;
            *(float4*)(o)      = (float4){acc[r][0][0], acc[r][0][1], acc[r][0][2], acc[r][0][3]};
            *(float4*)(o + 4)  = (float4){acc[r][0][4], acc[r][0][5], acc[r][1][0], acc[r][1][1]};
            *(float4*)(o + 8)  = (float4){acc[r][1][2], acc[r][1][3], acc[r][1][4], acc[r][1][5]};
            *(float4*)(o + 12) = (float4){acc[r][2][0], acc[r][2][1], acc[r][2][2], acc[r][2][3]};
            *(float4*)(o + 16) = (float4){acc[r][2][4], acc[r][2][5], s[r][0], s[r][1]};
        }
    }
}

// ---------------- Final: sum NS slab partials -> xagg + MFMA MLP tail -------
template<int NS>
__global__ __launch_bounds__(256)
void k_fin(const float* __restrict__ pw,
           const short* __restrict__ Wp,
           const float* __restrict__ W0, const float* __restrict__ b0,
           const float* __restrict__ b1, const float* __restrict__ b2,
           const float* __restrict__ Wpf, const float* __restrict__ bp,
           float* __restrict__ xagg, float* __restrict__ u_out) {
    __shared__ struct {
        float xa[8][DIN];
        short hA[16 * 256];
        short hB[16 * 256];
        float h3[16 * 257];
    } sm;
    __shared__ float tmp[8][20];
    const int tid  = threadIdx.x;
    const int lane = tid & 63;
    const int wave = tid >> 6;
    const int row0 = blockIdx.x * 8;

    if (tid < 160) {
        int r = tid / 20, e = tid - r * 20;
        float v = 0.f;
#pragma unroll
        for (int sIdx = 0; sIdx < NS; ++sIdx)
            v += pw[((size_t)sIdx * N + row0 + r) * 20 + e];
        tmp[r][e] = v;
    }
    __syncthreads();
    if (tid < 144) {
        int r = tid / 18, e = tid - r * 18;
        float s1 = tmp[r][18], s2 = tmp[r][19];
        float v;
        if (e < 6)       v = tmp[r][12 + e];
        else if (e < 12) v = tmp[r][e] * s2;
        else             v = tmp[r][e - 12] * s1 * s2;
        sm.xa[r][e] = v;
        xagg[(size_t)(row0 + r) * DIN + e] = v;
    }
    __syncthreads();

    { // layer 0 (K=18, f32 VALU)
        const int row = tid >> 5;
        const int n0  = (tid & 31) * 8;
        float accv[8];
#pragma unroll
        for (int jn = 0; jn < 8; ++jn) accv[jn] = b0[n0 + jn];
        for (int k = 0; k < DIN; ++k) {
            float4 wa = *(const float4*)&W0[k * HID + n0];
            float4 wb = *(const float4*)&W0[k * HID + n0 + 4];
            const float w[8] = {wa.x,wa.y,wa.z,wa.w, wb.x,wb.y,wb.z,wb.w};
            float xr = sm.xa[row][k];
#pragma unroll
            for (int jn = 0; jn < 8; ++jn) accv[jn] += xr * w[jn];
        }
        bf16x8 v;
#pragma unroll
        for (int jn = 0; jn < 8; ++jn) v[jn] = f2bf(fmaxf(accv[jn], 0.f));
        *(bf16x8*)&sm.hA[(row * 256 + n0) ^ ((row & 7) << 3)] = v;
    }
    __syncthreads();

    const int arow = lane & 15;
    const int kgrp = (lane >> 4) << 3;
    const int wv   = wave;
#pragma unroll 1
    for (int L = 0; L < 2; ++L) {
        const short* hsrc = L ? sm.hB : sm.hA;
        const float* bias = L ? b2 : b1;
        const short* WpL  = Wp + L * 65536;

        bf16x8 Af[8];
#pragma unroll
        for (int ks = 0; ks < 8; ++ks)
            Af[ks] = *(const bf16x8*)&hsrc[(arow * 256 + ks * 32 + kgrp) ^ ((arow & 7) << 3)];

        f32x4 c4[4];
#pragma unroll
        for (int jt = 0; jt < 4; ++jt) {
            float b = bias[wv * 64 + jt * 16 + (lane & 15)];
            c4[jt] = (f32x4){b, b, b, b};
        }
#pragma unroll
        for (int ks = 0; ks < 8; ++ks) {
#pragma unroll
            for (int jt = 0; jt < 4; ++jt) {
                int j = wv * 4 + jt;
                bf16x8 Bf = *(const bf16x8*)&WpL[(((ks * 16 + j) * 64) + lane) * 8];
                c4[jt] = __builtin_amdgcn_mfma_f32_16x16x32_bf16(Af[ks], Bf, c4[jt], 0, 0, 0);
            }
        }
#pragma unroll
        for (int jt = 0; jt < 4; ++jt) {
            int n = wv * 64 + jt * 16 + (lane & 15);
#pragma unroll
            for (int q = 0; q < 4; ++q) {
                int row = ((lane >> 4) << 2) + q;
                float v = fmaxf(c4[jt][q], 0.f);
                if (L == 0) sm.hB[(row * 256 + n) ^ ((row & 7) << 3)] = f2bf(v);
                else        sm.h3[row * 257 + n] = v;
            }
        }
        __syncthreads();
    }

    if (tid < 128) {
        const int r  = tid >> 4;
        const int d  = (tid >> 3) & 1;
        const int ks = tid & 7;
        float accf = 0.f;
        const float* hr = &sm.h3[r * 257 + ks * 32];
#pragma unroll
        for (int i = 0; i < 32; ++i) accf += hr[i] * Wpf[(ks * 32 + i) * DOUT + d];
        accf += __shfl_xor(accf, 1, 64);
        accf += __shfl_xor(accf, 2, 64);
        accf += __shfl_xor(accf, 4, 64);
        if (ks == 0) u_out[(size_t)(row0 + r) * DOUT + d] = accf + bp[d];
    }
}

extern "C" void kernel_launch(void* const* d_in, const int* in_sizes, int n_in,
                              void* d_out, int out_size, void* d_ws, size_t ws_size,
                              hipStream_t stream) {
    const float* vis  = (const float*)d_in[0];
    const float* anet = (const float*)d_in[1];
    const float* Wv   = (const float*)d_in[2];
    const float* bv   = (const float*)d_in[3];
    const float* W0   = (const float*)d_in[4];
    const float* b0   = (const float*)d_in[5];
    const float* W1   = (const float*)d_in[6];
    const float* b1   = (const float*)d_in[7];
    const float* W2   = (const float*)d_in[8];
    const float* b2   = (const float*)d_in[9];
    const float* Wpf  = (const float*)d_in[10];
    const float* bp   = (const float*)d_in[11];

    float* xagg  = (float*)d_out;                  // 4096*18
    float* u_out = (float*)d_out + (size_t)N*DIN;  // 4096*2

    // ws layout
    float* xallT = (float*)d_ws;                               // 288 KB linear (fallback)
    float* xsw   = (float*)((char*)d_ws + (288 << 10));        // 344 KB swizzled slabs
    short* Wpk   = (short*)((char*)d_ws + (640 << 10));        // 256 KB bf16 frags
    float* pw    = (float*)((char*)d_ws + (896 << 10));        // 8*4096*20 f32 = 2.5 MB

    const size_t need_new = (896 << 10) + (size_t)NSLAB * N * 20 * sizeof(float);
    const size_t need_old = (896 << 10) + (size_t)2 * N * 20 * sizeof(float);

    if (ws_size >= need_new) {
        k_prep<<<800, 256, 0, stream>>>(vis, Wv, bv, xallT, xsw, W1, W2, Wpk);
        k_msga<<<512 * NSLAB, 256, 0, stream>>>(anet, xsw, pw);
        k_fin<NSLAB><<<N / 8, 256, 0, stream>>>(pw, Wpk, W0, b0, b1, b2, Wpf, bp, xagg, u_out);
    } else if (ws_size >= need_old) {
        k_prep<<<800, 256, 0, stream>>>(vis, Wv, bv, xallT, xsw, W1, W2, Wpk);
        k_msg2<<<1024, 256, 0, stream>>>(anet, xallT, pw);
        k_fin<2><<<N / 8, 256, 0, stream>>>(pw, Wpk, W0, b0, b1, b2, Wpf, bp, xagg, u_out);
    }
}